// Round 1
// baseline (298.949 us; speedup 1.0000x reference)
//
#include <hip/hip_runtime.h>
#include <stdint.h>

// ---------------------------------------------------------------------------
// BondPoolingLayer: out[e] = MLP(cat(h[src],h[dst])) + MLP(cat(h[dst],h[src]))
// MLP: 256 ->(W1,b1,relu) 128 ->(W2,b2,relu) 128 ->(W3,b3) 2
//
// Restructuring: P[n, 0:128] = h[n] @ W1_top ; P[n,128:256] = h[n] @ W1_bot + b1
//   fwd layer1 preact = P[s,0:128] + P[d,128:256]
//   rev layer1 preact = P[d,0:128] + P[s,128:256]
// Then per edge-direction row: relu -> @W2+b2 relu -> @W3, sum fwd+rev (+2*b3).
// ---------------------------------------------------------------------------

typedef __attribute__((ext_vector_type(8))) short bf16x8;
typedef __attribute__((ext_vector_type(4))) float f32x4;

__device__ __forceinline__ unsigned short f2bf(float f) {
    union { float f; unsigned u; } v; v.f = f;
    unsigned u = v.u;
    unsigned r = u + 0x7FFFu + ((u >> 16) & 1u);   // RNE
    return (unsigned short)(r >> 16);
}
__device__ __forceinline__ float bf2f(unsigned u16) {
    union { unsigned u; float f; } v; v.u = u16 << 16;
    return v.f;
}

// XOR swizzle: LDS tiles are [128 rows][128 bf16], chunk = 8 bf16 (16B).
// index (ushort units) for (row, chunk in [0,16))
__device__ __forceinline__ int sw_idx(int row, int chunk) {
    return row * 128 + ((chunk ^ (row & 7)) << 3);
}

// add two bf16 pairs in fp32, relu, repack
__device__ __forceinline__ unsigned addrelu2(unsigned a, unsigned b) {
    float a0 = bf2f(a & 0xFFFFu), a1 = bf2f(a >> 16);
    float b0 = bf2f(b & 0xFFFFu), b1v = bf2f(b >> 16);
    float r0 = fmaxf(a0 + b0, 0.f);
    float r1 = fmaxf(a1 + b1v, 0.f);
    return (unsigned)f2bf(r0) | ((unsigned)f2bf(r1) << 16);
}

// ---------------------------------------------------------------------------
// Kernel 0: weight prep.
// W1t[j][k] (j in [0,256), k in [0,128)) = W1cat[k][j]
//   where W1cat[k][j] = W1[k][j] (j<128) else W1[k+128][j-128]
// W2t[n][k] = W2[k][n]
// ---------------------------------------------------------------------------
__global__ void prep_weights(const float* __restrict__ W1,
                             const float* __restrict__ W2,
                             unsigned short* __restrict__ W1t,
                             unsigned short* __restrict__ W2t) {
    int idx = blockIdx.x * 256 + threadIdx.x;
    if (idx < 256 * 128) {
        int j = idx >> 7, k = idx & 127;
        float v = (j < 128) ? W1[k * 128 + j] : W1[(k + 128) * 128 + (j - 128)];
        W1t[idx] = f2bf(v);
    } else {
        int i2 = idx - 256 * 128;
        if (i2 < 128 * 128) {
            int n = i2 >> 7, k = i2 & 127;
            W2t[i2] = f2bf(W2[k * 128 + n]);
        }
    }
}

// ---------------------------------------------------------------------------
// Kernel A: node projection GEMM.  P[n][0:256] bf16, b1 folded into cols>=128.
// Tile: 128 rows x 256 cols (two 128-col B tiles), K=128. 4 waves.
// ---------------------------------------------------------------------------
__global__ __launch_bounds__(256, 2) void node_proj(
    const float* __restrict__ h, const unsigned short* __restrict__ W1t,
    const float* __restrict__ b1, unsigned short* __restrict__ P, int nodes) {
    __shared__ unsigned short Abuf[128 * 128];
    __shared__ unsigned short Bbuf[128 * 128];

    int t = threadIdx.x;
    int lane = t & 63;
    int w = t >> 6;
    int ml = lane & 15, quad = lane >> 4;
    int mbase = blockIdx.x * 128;

    // stage A: h rows -> bf16 LDS (swizzled)
    {
        int r = t >> 1, half = t & 1;
        int row = mbase + r; if (row >= nodes) row = nodes - 1;
        const float4* src = (const float4*)(h + (size_t)row * 128 + half * 64);
#pragma unroll
        for (int i = 0; i < 8; ++i) {
            float4 a = src[2 * i], b = src[2 * i + 1];
            uint4 o;
            o.x = (unsigned)f2bf(a.x) | ((unsigned)f2bf(a.y) << 16);
            o.y = (unsigned)f2bf(a.z) | ((unsigned)f2bf(a.w) << 16);
            o.z = (unsigned)f2bf(b.x) | ((unsigned)f2bf(b.y) << 16);
            o.w = (unsigned)f2bf(b.z) | ((unsigned)f2bf(b.w) << 16);
            *(uint4*)(Abuf + sw_idx(r, half * 8 + i)) = o;
        }
    }

    for (int nt = 0; nt < 2; ++nt) {
        // stage B tile (already transposed in global): rows j = nt*128 + r
        {
            int r = t >> 1, half = t & 1;
            const uint4* src = (const uint4*)(W1t + ((size_t)(nt * 128 + r)) * 128 + half * 64);
#pragma unroll
            for (int i = 0; i < 8; ++i)
                *(uint4*)(Bbuf + sw_idx(r, half * 8 + i)) = src[i];
        }
        __syncthreads();

        f32x4 acc[2][8] = {};
#pragma unroll
        for (int kk = 0; kk < 4; ++kk) {
            bf16x8 afrag[2], bfrag[8];
            int chunk = kk * 4 + quad;
#pragma unroll
            for (int rt = 0; rt < 2; ++rt)
                afrag[rt] = *(const bf16x8*)(Abuf + sw_idx(w * 32 + rt * 16 + ml, chunk));
#pragma unroll
            for (int ct = 0; ct < 8; ++ct)
                bfrag[ct] = *(const bf16x8*)(Bbuf + sw_idx(ct * 16 + ml, chunk));
#pragma unroll
            for (int rt = 0; rt < 2; ++rt)
#pragma unroll
                for (int ct = 0; ct < 8; ++ct)
                    acc[rt][ct] = __builtin_amdgcn_mfma_f32_16x16x32_bf16(
                        afrag[rt], bfrag[ct], acc[rt][ct], 0, 0, 0);
        }
        __syncthreads();   // done with LDS for this nt

        // epilogue: (+ b1 for cols >= 128) -> bf16 store
#pragma unroll
        for (int rt = 0; rt < 2; ++rt) {
#pragma unroll
            for (int reg = 0; reg < 4; ++reg) {
                int rloc = w * 32 + rt * 16 + quad * 4 + reg;
                int node = mbase + rloc;
                if (node < nodes) {
#pragma unroll
                    for (int ct = 0; ct < 8; ++ct) {
                        int col = nt * 128 + ct * 16 + ml;
                        float v = acc[rt][ct][reg];
                        if (nt == 1) v += b1[ct * 16 + ml];
                        P[(size_t)node * 256 + col] = f2bf(v);
                    }
                }
            }
        }
    }
}

// ---------------------------------------------------------------------------
// Kernel B: per-edge MLP.  64 edges/WG -> 128 rows (r<64 fwd, r>=64 rev).
// Z = relu(P[xa,0:128] + P[xb,128:256]) in LDS; H2 = relu(Z@W2t + b2);
// y = H2@W3; rev rows summed into fwd rows via LDS; write out once.
// ---------------------------------------------------------------------------
__global__ __launch_bounds__(256, 2) void edge_mlp(
    const unsigned short* __restrict__ P, const int* __restrict__ src,
    const int* __restrict__ dst, const unsigned short* __restrict__ W2t,
    const float* __restrict__ b2, const float* __restrict__ W3,
    const float* __restrict__ b3, float* __restrict__ out, int E) {
    __shared__ unsigned short Zbuf[128 * 128];
    __shared__ unsigned short W2s[128 * 128];

    int t = threadIdx.x;
    int lane = t & 63;
    int w = t >> 6;
    int ml = lane & 15, quad = lane >> 4;
    int ebase = blockIdx.x * 64;

    // stage W2 (transposed, bf16) into LDS
    {
        int r = t >> 1, half = t & 1;
        const uint4* s = (const uint4*)(W2t + (size_t)r * 128 + half * 64);
#pragma unroll
        for (int i = 0; i < 8; ++i)
            *(uint4*)(W2s + sw_idx(r, half * 8 + i)) = s[i];
    }
    // build Z via gathers (b1 already folded into P's second half)
    {
        int r = t >> 1, half = t & 1;
        int le = r & 63;
        int e = ebase + le; if (e >= E) e = E - 1;
        int si = src[e], di = dst[e];
        int xa = (r < 64) ? si : di;
        int xb = (r < 64) ? di : si;
        const uint4* Pa = (const uint4*)(P + (size_t)xa * 256 + half * 64);
        const uint4* Pb = (const uint4*)(P + (size_t)xb * 256 + 128 + half * 64);
#pragma unroll
        for (int i = 0; i < 8; ++i) {
            uint4 av = Pa[i], bv = Pb[i];
            uint4 o;
            o.x = addrelu2(av.x, bv.x);
            o.y = addrelu2(av.y, bv.y);
            o.z = addrelu2(av.z, bv.z);
            o.w = addrelu2(av.w, bv.w);
            *(uint4*)(Zbuf + sw_idx(r, half * 8 + i)) = o;
        }
    }
    __syncthreads();

    f32x4 acc[2][8] = {};
#pragma unroll
    for (int kk = 0; kk < 4; ++kk) {
        bf16x8 afrag[2], bfrag[8];
        int chunk = kk * 4 + quad;
#pragma unroll
        for (int rt = 0; rt < 2; ++rt)
            afrag[rt] = *(const bf16x8*)(Zbuf + sw_idx(w * 32 + rt * 16 + ml, chunk));
#pragma unroll
        for (int ct = 0; ct < 8; ++ct)
            bfrag[ct] = *(const bf16x8*)(W2s + sw_idx(ct * 16 + ml, chunk));
#pragma unroll
        for (int rt = 0; rt < 2; ++rt)
#pragma unroll
            for (int ct = 0; ct < 8; ++ct)
                acc[rt][ct] = __builtin_amdgcn_mfma_f32_16x16x32_bf16(
                    afrag[rt], bfrag[ct], acc[rt][ct], 0, 0, 0);
    }

    // epilogue: +b2, relu, dot with W3 columns, butterfly-reduce over 16 lanes
    float w30[8], w31[8], b2v[8];
#pragma unroll
    for (int ct = 0; ct < 8; ++ct) {
        int c = ct * 16 + ml;
        w30[ct] = W3[c * 2 + 0];
        w31[ct] = W3[c * 2 + 1];
        b2v[ct] = b2[c];
    }
    float p0[2][4], p1[2][4];
#pragma unroll
    for (int rt = 0; rt < 2; ++rt)
#pragma unroll
        for (int reg = 0; reg < 4; ++reg) { p0[rt][reg] = 0.f; p1[rt][reg] = 0.f; }
#pragma unroll
    for (int rt = 0; rt < 2; ++rt)
#pragma unroll
        for (int ct = 0; ct < 8; ++ct)
#pragma unroll
            for (int reg = 0; reg < 4; ++reg) {
                float h2 = fmaxf(acc[rt][ct][reg] + b2v[ct], 0.f);
                p0[rt][reg] += h2 * w30[ct];
                p1[rt][reg] += h2 * w31[ct];
            }
#pragma unroll
    for (int m = 1; m < 16; m <<= 1) {
#pragma unroll
        for (int rt = 0; rt < 2; ++rt)
#pragma unroll
            for (int reg = 0; reg < 4; ++reg) {
                p0[rt][reg] += __shfl_xor(p0[rt][reg], m);
                p1[rt][reg] += __shfl_xor(p1[rt][reg], m);
            }
    }

    // rev rows -> LDS (reuse Zbuf storage; all Z reads are done, but barrier
    // first so no wave is still ds_read-ing Zbuf in its MFMA loop)
    __syncthreads();
    float* yrev = (float*)Zbuf;   // [64][2]
    if (w >= 2 && ml == 0) {
#pragma unroll
        for (int rt = 0; rt < 2; ++rt)
#pragma unroll
            for (int reg = 0; reg < 4; ++reg) {
                int r = w * 32 + rt * 16 + quad * 4 + reg;   // 64..127
                yrev[(r - 64) * 2 + 0] = p0[rt][reg];
                yrev[(r - 64) * 2 + 1] = p1[rt][reg];
            }
    }
    __syncthreads();
    if (w < 2 && ml == 0) {
        float bb0 = 2.f * b3[0], bb1 = 2.f * b3[1];
#pragma unroll
        for (int rt = 0; rt < 2; ++rt)
#pragma unroll
            for (int reg = 0; reg < 4; ++reg) {
                int r = w * 32 + rt * 16 + quad * 4 + reg;   // 0..63
                int e = ebase + r;
                if (e < E) {
                    out[(size_t)e * 2 + 0] = p0[rt][reg] + yrev[r * 2 + 0] + bb0;
                    out[(size_t)e * 2 + 1] = p1[rt][reg] + yrev[r * 2 + 1] + bb1;
                }
            }
    }
}

// ---------------------------------------------------------------------------
extern "C" void kernel_launch(void* const* d_in, const int* in_sizes, int n_in,
                              void* d_out, int out_size, void* d_ws, size_t ws_size,
                              hipStream_t stream) {
    (void)n_in; (void)out_size; (void)ws_size;
    const float* h  = (const float*)d_in[0];
    const int*   sr = (const int*)d_in[1];
    const int*   ds = (const int*)d_in[2];
    const float* W1 = (const float*)d_in[3];
    const float* b1 = (const float*)d_in[4];
    const float* W2 = (const float*)d_in[5];
    const float* b2 = (const float*)d_in[6];
    const float* W3 = (const float*)d_in[7];
    const float* b3 = (const float*)d_in[8];
    float* out = (float*)d_out;

    int nodes = in_sizes[0] / 128;
    int E = in_sizes[1];

    unsigned short* W1t = (unsigned short*)d_ws;          // 256*128
    unsigned short* W2t = W1t + 256 * 128;                // 128*128
    unsigned short* P   = W2t + 128 * 128;                // nodes*256

    prep_weights<<<(256 * 128 + 128 * 128 + 255) / 256, 256, 0, stream>>>(W1, W2, W1t, W2t);

    int mtiles = (nodes + 127) / 128;
    node_proj<<<mtiles, 256, 0, stream>>>(h, W1t, b1, P, nodes);

    int etiles = (E + 63) / 64;
    edge_mlp<<<etiles, 256, 0, stream>>>(P, sr, ds, W2t, b2, W3, b3, out, E);
}